// Round 15
// baseline (355.902 us; speedup 1.0000x reference)
//
#include <hip/hip_runtime.h>
#include <cstddef>

#define LEAKY 0.2f
#define EPS_DEN 1e-16f

typedef short bf8_t __attribute__((ext_vector_type(8)));   // 8 bf16 in 4 VGPRs
typedef float f4_t __attribute__((ext_vector_type(4)));
typedef unsigned short us4_t __attribute__((ext_vector_type(4)));

__device__ __forceinline__ unsigned short f2bf(float f) {   // RNE
    unsigned u = __float_as_uint(f);
    unsigned r = (u + 0x7fffu + ((u >> 16) & 1u)) >> 16;
    return (unsigned short)r;
}
__device__ __forceinline__ float bf2f(unsigned short h) {
    return __uint_as_float(((unsigned)h) << 16);
}

// ---------------------------------------------------------------------------
// CSR build: (hist merged into split_all) -> scan1 -> scan3b -> scatter
// ---------------------------------------------------------------------------
__global__ void scan1_kernel(int* __restrict__ cnt, int* __restrict__ bsum, int N) {
    __shared__ int s[256];
    int t = threadIdx.x;
    int i = blockIdx.x * 256 + t;
    int v = (i < N) ? cnt[i] : 0;
    s[t] = v;
    __syncthreads();
#pragma unroll
    for (int st = 1; st < 256; st <<= 1) {
        int add = (t >= st) ? s[t - st] : 0;
        __syncthreads();
        s[t] += add;
        __syncthreads();
    }
    if (i < N) cnt[i] = s[t] - v;
    if (t == 255) bsum[blockIdx.x] = s[255];
}

__global__ void scan3b_kernel(int* __restrict__ cnt, const int* __restrict__ bsum,
                              int* __restrict__ offs, int N, int NB) {
    __shared__ int sPre[64];
    __shared__ int sTot;
    int t = threadIdx.x;
    if (t < 64) {
        int v = (t < NB) ? bsum[t] : 0;
        int inc = v;
#pragma unroll
        for (int off = 1; off < 64; off <<= 1) {
            int u = __shfl_up(inc, off);
            if (t >= off) inc += u;
        }
        sPre[t] = inc - v;
        if (t == 63) sTot = inc;
    }
    __syncthreads();
    int i = blockIdx.x * 256 + t;
    if (i < N) {
        int o = cnt[i] + sPre[blockIdx.x];
        offs[i] = o;
        cnt[i] = o;
    }
    if (blockIdx.x == 0 && t == 0) offs[N] = sTot;
}

__global__ void scatter_kernel(const int* __restrict__ src, const int* __restrict__ dst,
                               int* __restrict__ cursor, int* __restrict__ csrc, int E) {
    int i = blockIdx.x * blockDim.x + threadIdx.x;
    if (i < E) {
        int d = dst[i];
        int pos = atomicAdd(&cursor[d], 1);
        csrc[pos] = src[i];
    }
}

// ---------------------------------------------------------------------------
// Merged kernel: edge histogram + x/W splits (all input-only work, 1 dispatch).
// Block ranges: [0,EB) hist, [EB,+NBX) x, then W1T, W2T, W3T.
// ---------------------------------------------------------------------------
__global__ void hist_split_kernel(
    const int* __restrict__ dst, int* __restrict__ counts, int E, int EB,
    const float* __restrict__ x, unsigned short* __restrict__ xh, unsigned short* __restrict__ xl,
    int NBX,
    const float* __restrict__ W1, unsigned short* __restrict__ w1h, unsigned short* __restrict__ w1l,
    const float* __restrict__ W2, unsigned short* __restrict__ w2h, unsigned short* __restrict__ w2l,
    const float* __restrict__ W3, unsigned short* __restrict__ w3h, unsigned short* __restrict__ w3l) {
    int b = blockIdx.x, t = threadIdx.x;
    if (b < EB) {
        int i = b * 256 + t;
        if (i < E) atomicAdd(&counts[dst[i]], 1);
        return;
    }
    b -= EB;
    float v;
    unsigned short* ph;
    unsigned short* pl;
    int out;
    if (b < NBX) {
        int idx = b * 256 + t;
        v = x[idx];
        out = idx;
        ph = xh; pl = xl;
    } else if (b < NBX + 512) {                 // W1 [256,512] -> W1^T [512,256]
        int idx = (b - NBX) * 256 + t;
        v = W1[idx];
        int k = idx >> 9, n = idx & 511;
        out = n * 256 + k;
        ph = w1h; pl = w1l;
    } else if (b < NBX + 512 + 1024) {          // W2 [512,512] -> W2^T
        int idx = (b - NBX - 512) * 256 + t;
        v = W2[idx];
        int k = idx >> 9, n = idx & 511;
        out = n * 512 + k;
        ph = w2h; pl = w2l;
    } else {                                    // W3 [512,128] -> W3^T [128,512]
        int idx = (b - NBX - 1536) * 256 + t;
        v = W3[idx];
        int k = idx >> 7, n = idx & 127;
        out = n * 512 + k;
        ph = w3h; pl = w3l;
    }
    unsigned short hv = f2bf(v);
    ph[out] = hv;
    pl[out] = f2bf(v - bf2f(hv));
}

// ---------------------------------------------------------------------------
// MFMA GEMM (split-bf16, single-staged), 128x128 tile, BK=64 (R14).
// EPILOGUE: computes als/ald for its 128 rows (block cols == one head).
// ---------------------------------------------------------------------------
__global__ __launch_bounds__(256) void mfma_gemm128_kernel(
    const unsigned short* __restrict__ Ahi, const unsigned short* __restrict__ Alo,
    const unsigned short* __restrict__ BThi, const unsigned short* __restrict__ BTlo,
    const float* __restrict__ a_src, const float* __restrict__ a_dst,
    float* __restrict__ C, float* __restrict__ als, float* __restrict__ ald,
    int M, int N, int K) {
    constexpr int BK = 64;
    __shared__ __align__(16) unsigned short sAh[128 * BK];
    __shared__ __align__(16) unsigned short sAl[128 * BK];
    __shared__ __align__(16) unsigned short sBh[128 * BK];
    __shared__ __align__(16) unsigned short sBl[128 * BK];
    __shared__ float sAls[128][2];
    __shared__ float sAld[128][2];
    int t = threadIdx.x;
    int w = t >> 6, lane = t & 63;
    int quad = lane >> 4, low = lane & 15;
    int m0 = blockIdx.y * 128, n0 = blockIdx.x * 128;
    int wm = (w & 1) * 64, wn = (w >> 1) * 64;

    f4_t acc[4][4];
#pragma unroll
    for (int i = 0; i < 4; i++)
#pragma unroll
        for (int j = 0; j < 4; j++) acc[i][j] = (f4_t){0.f, 0.f, 0.f, 0.f};

    int srow = lane >> 3;     // 0..7
    int schunk = lane & 7;    // 0..7

    for (int k0 = 0; k0 < K; k0 += BK) {
        __syncthreads();
#pragma unroll
        for (int inst = 0; inst < 4; inst++) {
            int rl = w * 32 + inst * 8 + srow;
            int gm = m0 + rl;
            if (gm >= M) gm = M - 1;
            size_t goff = (size_t)gm * K + k0 + schunk * 8;
            size_t loff = (size_t)(w * 32 + inst * 8) * 128;
            __builtin_amdgcn_global_load_lds(
                (const __attribute__((address_space(1))) void*)(Ahi + goff),
                (__attribute__((address_space(3))) void*)((char*)sAh + loff), 16, 0, 0);
            __builtin_amdgcn_global_load_lds(
                (const __attribute__((address_space(1))) void*)(Alo + goff),
                (__attribute__((address_space(3))) void*)((char*)sAl + loff), 16, 0, 0);
        }
#pragma unroll
        for (int inst = 0; inst < 4; inst++) {
            int rl = w * 32 + inst * 8 + srow;
            int gn = n0 + rl;
            size_t goff = (size_t)gn * K + k0 + schunk * 8;
            size_t loff = (size_t)(w * 32 + inst * 8) * 128;
            __builtin_amdgcn_global_load_lds(
                (const __attribute__((address_space(1))) void*)(BThi + goff),
                (__attribute__((address_space(3))) void*)((char*)sBh + loff), 16, 0, 0);
            __builtin_amdgcn_global_load_lds(
                (const __attribute__((address_space(1))) void*)(BTlo + goff),
                (__attribute__((address_space(3))) void*)((char*)sBl + loff), 16, 0, 0);
        }
        __syncthreads();

#pragma unroll
        for (int ks = 0; ks < 2; ks++) {
            int ko = ks * 32 + quad * 8;
            bf8_t afh[4], bfh[4], xx[4];
#pragma unroll
            for (int i = 0; i < 4; i++) {
                int row = wm + i * 16 + low;
                afh[i] = *(const bf8_t*)&sAh[row * BK + ko];
            }
#pragma unroll
            for (int j = 0; j < 4; j++) {
                int row = wn + j * 16 + low;
                bfh[j] = *(const bf8_t*)&sBh[row * BK + ko];
            }
#pragma unroll
            for (int i = 0; i < 4; i++)
#pragma unroll
                for (int j = 0; j < 4; j++)
                    acc[i][j] = __builtin_amdgcn_mfma_f32_16x16x32_bf16(afh[i], bfh[j], acc[i][j], 0, 0, 0);
#pragma unroll
            for (int j = 0; j < 4; j++) {
                int row = wn + j * 16 + low;
                xx[j] = *(const bf8_t*)&sBl[row * BK + ko];
            }
#pragma unroll
            for (int i = 0; i < 4; i++)
#pragma unroll
                for (int j = 0; j < 4; j++)
                    acc[i][j] = __builtin_amdgcn_mfma_f32_16x16x32_bf16(afh[i], xx[j], acc[i][j], 0, 0, 0);
#pragma unroll
            for (int i = 0; i < 4; i++) {
                int row = wm + i * 16 + low;
                xx[i] = *(const bf8_t*)&sAl[row * BK + ko];
            }
#pragma unroll
            for (int i = 0; i < 4; i++)
#pragma unroll
                for (int j = 0; j < 4; j++)
                    acc[i][j] = __builtin_amdgcn_mfma_f32_16x16x32_bf16(xx[i], bfh[j], acc[i][j], 0, 0, 0);
        }
    }

    // C store
#pragma unroll
    for (int i = 0; i < 4; i++) {
#pragma unroll
        for (int r = 0; r < 4; r++) {
            int gm = m0 + wm + i * 16 + quad * 4 + r;
            if (gm >= M) continue;
#pragma unroll
            for (int j = 0; j < 4; j++) {
                int gn = n0 + wn + j * 16 + low;
                C[(size_t)gm * N + gn] = acc[i][j][r];
            }
        }
    }

    // epilogue: als/ald for this block's rows; head = n0>>7
    int hd = n0 >> 7;
    float as_[4], ad_[4];
#pragma unroll
    for (int j = 0; j < 4; j++) {
        int c = wn + j * 16 + low;
        as_[j] = a_src[hd * 128 + c];
        ad_[j] = a_dst[hd * 128 + c];
    }
    int chh = wn >> 6;
#pragma unroll
    for (int i = 0; i < 4; i++) {
#pragma unroll
        for (int r = 0; r < 4; r++) {
            float v = acc[i][0][r] * as_[0] + acc[i][1][r] * as_[1] +
                      acc[i][2][r] * as_[2] + acc[i][3][r] * as_[3];
            float vd = acc[i][0][r] * ad_[0] + acc[i][1][r] * ad_[1] +
                       acc[i][2][r] * ad_[2] + acc[i][3][r] * ad_[3];
#pragma unroll
            for (int off = 1; off < 16; off <<= 1) {
                v += __shfl_xor(v, off);
                vd += __shfl_xor(vd, off);
            }
            if (low == 0) {
                int row = wm + i * 16 + quad * 4 + r;
                sAls[row][chh] = v;
                sAld[row][chh] = vd;
            }
        }
    }
    __syncthreads();
    if (t < 128) {
        int gm = m0 + t;
        if (gm < M) {
            als[gm * 4 + hd] = sAls[t][0] + sAls[t][1];
            ald[gm * 4 + hd] = sAld[t][0] + sAld[t][1];
        }
    }
}

// 64x128 variant for layer 3 (BK=32) + als epilogue.
__global__ __launch_bounds__(256) void mfma_gemm64_kernel(
    const unsigned short* __restrict__ Ahi, const unsigned short* __restrict__ Alo,
    const unsigned short* __restrict__ BThi, const unsigned short* __restrict__ BTlo,
    const float* __restrict__ a_src, const float* __restrict__ a_dst,
    float* __restrict__ C, float* __restrict__ als, float* __restrict__ ald,
    int M, int N, int K) {
    constexpr int BK = 32;
    __shared__ __align__(16) unsigned short sAh[64 * BK];
    __shared__ __align__(16) unsigned short sAl[64 * BK];
    __shared__ __align__(16) unsigned short sBh[128 * BK];
    __shared__ __align__(16) unsigned short sBl[128 * BK];
    __shared__ float sAls[64][2];
    __shared__ float sAld[64][2];
    int t = threadIdx.x;
    int w = t >> 6, lane = t & 63;
    int quad = lane >> 4, low = lane & 15;
    int m0 = blockIdx.y * 64, n0 = blockIdx.x * 128;
    int wm = (w & 1) * 32, wn = (w >> 1) * 64;

    f4_t acc[2][4];
#pragma unroll
    for (int i = 0; i < 2; i++)
#pragma unroll
        for (int j = 0; j < 4; j++) acc[i][j] = (f4_t){0.f, 0.f, 0.f, 0.f};

    int srow = lane >> 2;
    int schunk = lane & 3;

    for (int k0 = 0; k0 < K; k0 += BK) {
        __syncthreads();
        {
            int gm = m0 + w * 16 + srow;
            if (gm >= M) gm = M - 1;
            size_t goff = (size_t)gm * K + k0 + schunk * 8;
            size_t loff = (size_t)(w * 1024);
            __builtin_amdgcn_global_load_lds(
                (const __attribute__((address_space(1))) void*)(Ahi + goff),
                (__attribute__((address_space(3))) void*)((char*)sAh + loff), 16, 0, 0);
            __builtin_amdgcn_global_load_lds(
                (const __attribute__((address_space(1))) void*)(Alo + goff),
                (__attribute__((address_space(3))) void*)((char*)sAl + loff), 16, 0, 0);
        }
#pragma unroll
        for (int inst = 0; inst < 2; inst++) {
            int gn = n0 + w * 32 + inst * 16 + srow;
            size_t goff = (size_t)gn * K + k0 + schunk * 8;
            size_t loff = (size_t)(w * 2048 + inst * 1024);
            __builtin_amdgcn_global_load_lds(
                (const __attribute__((address_space(1))) void*)(BThi + goff),
                (__attribute__((address_space(3))) void*)((char*)sBh + loff), 16, 0, 0);
            __builtin_amdgcn_global_load_lds(
                (const __attribute__((address_space(1))) void*)(BTlo + goff),
                (__attribute__((address_space(3))) void*)((char*)sBl + loff), 16, 0, 0);
        }
        __syncthreads();

        bf8_t afh[2], bfh[4], xx[4];
#pragma unroll
        for (int i = 0; i < 2; i++) {
            int row = wm + i * 16 + low;
            afh[i] = *(const bf8_t*)&sAh[row * BK + quad * 8];
        }
#pragma unroll
        for (int j = 0; j < 4; j++) {
            int row = wn + j * 16 + low;
            bfh[j] = *(const bf8_t*)&sBh[row * BK + quad * 8];
        }
#pragma unroll
        for (int i = 0; i < 2; i++)
#pragma unroll
            for (int j = 0; j < 4; j++)
                acc[i][j] = __builtin_amdgcn_mfma_f32_16x16x32_bf16(afh[i], bfh[j], acc[i][j], 0, 0, 0);
#pragma unroll
        for (int j = 0; j < 4; j++) {
            int row = wn + j * 16 + low;
            xx[j] = *(const bf8_t*)&sBl[row * BK + quad * 8];
        }
#pragma unroll
        for (int i = 0; i < 2; i++)
#pragma unroll
            for (int j = 0; j < 4; j++)
                acc[i][j] = __builtin_amdgcn_mfma_f32_16x16x32_bf16(afh[i], xx[j], acc[i][j], 0, 0, 0);
#pragma unroll
        for (int i = 0; i < 2; i++) {
            int row = wm + i * 16 + low;
            xx[i] = *(const bf8_t*)&sAl[row * BK + quad * 8];
        }
#pragma unroll
        for (int i = 0; i < 2; i++)
#pragma unroll
            for (int j = 0; j < 4; j++)
                acc[i][j] = __builtin_amdgcn_mfma_f32_16x16x32_bf16(xx[i], bfh[j], acc[i][j], 0, 0, 0);
    }

#pragma unroll
    for (int i = 0; i < 2; i++) {
#pragma unroll
        for (int r = 0; r < 4; r++) {
            int gm = m0 + wm + i * 16 + quad * 4 + r;
            if (gm >= M) continue;
#pragma unroll
            for (int j = 0; j < 4; j++) {
                int gn = n0 + wn + j * 16 + low;
                C[(size_t)gm * N + gn] = acc[i][j][r];
            }
        }
    }

    float as_[4], ad_[4];
#pragma unroll
    for (int j = 0; j < 4; j++) {
        int c = wn + j * 16 + low;
        as_[j] = a_src[c];
        ad_[j] = a_dst[c];
    }
    int chh = wn >> 6;
#pragma unroll
    for (int i = 0; i < 2; i++) {
#pragma unroll
        for (int r = 0; r < 4; r++) {
            float v = acc[i][0][r] * as_[0] + acc[i][1][r] * as_[1] +
                      acc[i][2][r] * as_[2] + acc[i][3][r] * as_[3];
            float vd = acc[i][0][r] * ad_[0] + acc[i][1][r] * ad_[1] +
                       acc[i][2][r] * ad_[2] + acc[i][3][r] * ad_[3];
#pragma unroll
            for (int off = 1; off < 16; off <<= 1) {
                v += __shfl_xor(v, off);
                vd += __shfl_xor(vd, off);
            }
            if (low == 0) {
                int row = wm + i * 16 + quad * 4 + r;
                sAls[row][chh] = v;
                sAld[row][chh] = vd;
            }
        }
    }
    __syncthreads();
    if (t < 64) {
        int gm = m0 + t;
        if (gm < M) {
            als[gm] = sAls[t][0] + sAls[t][1];
            ald[gm] = sAld[t][0] + sAld[t][1];
        }
    }
}

// ---------------------------------------------------------------------------
// Softmax stats (h4) -> PACKED int2 {s*512, p} head-major pbuf2[hd*E+slot];
// psf = unnorm self weight; rden = 1/(sum+eps). Fast path deg<=64.
// ---------------------------------------------------------------------------
__global__ void stats_h4_kernel(const int* __restrict__ csrc, const int* __restrict__ offs,
                                const float* __restrict__ als, const float* __restrict__ ald,
                                int2* __restrict__ pbuf2, float* __restrict__ psf,
                                float* __restrict__ rden, int N, int E) {
    int wave = threadIdx.x >> 6, lane = threadIdx.x & 63;
    int n = blockIdx.x * 4 + wave;
    if (n >= N) return;
    int hd = lane & 3, es = lane >> 2;
    float aldn = ald[n * 4 + hd];
    float selfe = als[n * 4 + hd] + aldn;
    selfe = selfe > 0.f ? selfe : LEAKY * selfe;
    int beg = offs[n], end = offs[n + 1];
    int deg = end - beg;
    int2* pb = pbuf2 + (size_t)hd * E;
    float m = selfe;
    float d = 0.f;
    if (deg <= 64) {
        float eR[4];
        int sR[4];
        int nch = (deg + 15) >> 4;
        for (int k = 0; k < nch; k++) {
            int idx = beg + k * 16 + es;
            float e = -1e30f;
            int s = 0;
            if (idx < end) {
                s = csrc[idx];
                e = als[s * 4 + hd] + aldn;
                e = e > 0.f ? e : LEAKY * e;
                m = fmaxf(m, e);
            }
            eR[k] = e;
            sR[k] = s;
        }
#pragma unroll
        for (int off = 4; off < 64; off <<= 1) m = fmaxf(m, __shfl_xor(m, off));
        for (int k = 0; k < nch; k++) {
            int idx = beg + k * 16 + es;
            if (idx < end) {
                float p = __expf(eR[k] - m);
                pb[idx] = make_int2(sR[k] << 9, __float_as_int(p));
                d += p;
            }
        }
    } else {
        for (int base = beg; base + es < end; base += 16) {
            int idx = base + es;
            int s = csrc[idx];
            float e = als[s * 4 + hd] + aldn;
            e = e > 0.f ? e : LEAKY * e;
            pb[idx] = make_int2(s << 9, __float_as_int(e));
            m = fmaxf(m, e);
        }
#pragma unroll
        for (int off = 4; off < 64; off <<= 1) m = fmaxf(m, __shfl_xor(m, off));
        for (int base = beg; base + es < end; base += 16) {
            int idx = base + es;
            int2 se = pb[idx];
            float p = __expf(__int_as_float(se.y) - m);
            pb[idx] = make_int2(se.x, __float_as_int(p));
            d += p;
        }
    }
#pragma unroll
    for (int off = 4; off < 64; off <<= 1) d += __shfl_xor(d, off);
    float pself = __expf(selfe - m);
    float r = 1.0f / (d + pself + EPS_DEN);
    if (es == 0) {
        psf[n * 4 + hd] = pself;
        rden[n * 4 + hd] = r;
    }
}

// ---------------------------------------------------------------------------
// HALF-HEAD aggregate: R8 2-barrier structure (best measured) + packed int2
// staging (1 ds_read_b64/iter instead of 2 ds_read_b32). hh=blockIdx&7 keeps
// the 2.6MB L2 slice per XCD.
// ---------------------------------------------------------------------------
template <bool DO_ELU>
__global__ __launch_bounds__(64) void gat_agg_hh_kernel(
    const float* __restrict__ h, const int2* __restrict__ pbuf2,
    const float* __restrict__ psf, const float* __restrict__ rden,
    const int* __restrict__ offs, const float* __restrict__ bias,
    unsigned short* __restrict__ ohi, unsigned short* __restrict__ olo,
    int N, int E) {
    int gid = blockIdx.x;
    int hh = gid & 7;
    int n = gid >> 3;
    int head = hh >> 1;
    int lane = threadIdx.x;
    int eg = lane >> 4;                  // 0..3 edge groups
    int f0 = hh * 64 + (lane & 15) * 4;
    const int2* pb = pbuf2 + (size_t)head * E;

    __shared__ __align__(8) int2 sE[64];
    int beg = offs[n], end = offs[n + 1];

    f4_t acc = (f4_t){0.f, 0.f, 0.f, 0.f};
    for (int base = beg; base < end; base += 64) {
        int len = min(64, end - base);
        __syncthreads();
        if (lane < len) sE[lane] = pb[base + lane];
        __syncthreads();
#pragma unroll 8
        for (int c = eg; c < len; c += 4) {
            int2 se = sE[c];                       // ds_read_b64
            const float* srow = h + (size_t)(unsigned)se.x + f0;
            acc += __int_as_float(se.y) * *(const f4_t*)srow;
        }
    }
    if (eg == 0) {
        f4_t x = *(const f4_t*)(h + (size_t)n * 512 + f0);
        acc += psf[n * 4 + head] * x;
    }
#pragma unroll
    for (int j = 0; j < 4; j++) {
        acc[j] += __shfl_xor(acc[j], 16);
        acc[j] += __shfl_xor(acc[j], 32);
    }
    if (lane < 16) {
        float r = rden[n * 4 + head];
        f4_t b = *(const f4_t*)(bias + f0);
        us4_t hs, ls;
#pragma unroll
        for (int j = 0; j < 4; j++) {
            float o = acc[j] * r + b[j];
            if (DO_ELU) o = o > 0.f ? o : (__expf(o) - 1.0f);
            unsigned short hv = f2bf(o);
            hs[j] = hv;
            ls[j] = f2bf(o - bf2f(hv));
        }
        size_t idx = (size_t)n * 512 + f0;
        *(us4_t*)&ohi[idx] = hs;
        *(us4_t*)&olo[idx] = ls;
    }
}

// ---------------------------------------------------------------------------
// Layer-3: FUSED stats + aggregate + classifier; 4 nodes/block (256 thr),
// Wc1 staged in LDS. Per-wave gather via shfl with uniform trip counts.
// ---------------------------------------------------------------------------
__global__ __launch_bounds__(256) void gat_agg_h1_cls_kernel(
    const float* __restrict__ h, const float* __restrict__ als,
    const float* __restrict__ ald, const int* __restrict__ csrc,
    const int* __restrict__ offs, const float* __restrict__ bias,
    const float* __restrict__ Wc1, const float* __restrict__ bc1,
    const float* __restrict__ Wc2, const float* __restrict__ bc2,
    float* __restrict__ emb, float* __restrict__ outp, int N) {
    int tid = threadIdx.x;
    int wave = tid >> 6;
    int n = blockIdx.x * 4 + wave;
    int lane = tid & 63;
    int eg = lane >> 4;
    int fl = (lane & 15) * 8;
    __shared__ float sW[128 * 64];
    __shared__ float semb[4][128];

    for (int i = tid; i < 128 * 64; i += 256) sW[i] = Wc1[i];

    int beg = offs[n], end = offs[n + 1];
    int deg = end - beg;
    float aldn = ald[n];
    float selfe = als[n] + aldn;
    selfe = selfe > 0.f ? selfe : LEAKY * selfe;

    f4_t a0 = (f4_t){0.f, 0.f, 0.f, 0.f};
    f4_t a1 = (f4_t){0.f, 0.f, 0.f, 0.f};
    float d = 0.f;
    float m;

    if (deg <= 64) {
        float e = -1e30f;
        int s = 0;
        if (lane < deg) {
            s = csrc[beg + lane];
            e = als[s] + aldn;
            e = e > 0.f ? e : LEAKY * e;
        }
        m = fmaxf(e, selfe);
#pragma unroll
        for (int off = 1; off < 64; off <<= 1) m = fmaxf(m, __shfl_xor(m, off));
        float p = (lane < deg) ? __expf(e - m) : 0.f;
        d = p;
        int sreg = s << 7;
        int maxit = (deg + 3) >> 2;
#pragma unroll 4
        for (int i = 0; i < maxit; i++) {
            int c = eg + i * 4;
            int soff = __shfl(sreg, c);
            float pc = __shfl(p, c);
            const float* srow = h + (size_t)(unsigned)soff + fl;
            a0 += pc * *(const f4_t*)(srow);
            a1 += pc * *(const f4_t*)(srow + 4);
        }
    } else {
        m = selfe;
        for (int i = beg + lane; i < end; i += 64) {
            int s = csrc[i];
            float e = als[s] + aldn;
            e = e > 0.f ? e : LEAKY * e;
            m = fmaxf(m, e);
        }
#pragma unroll
        for (int off = 1; off < 64; off <<= 1) m = fmaxf(m, __shfl_xor(m, off));
        for (int base = beg; base < end; base += 64) {
            int len = min(64, end - base);
            int sreg = 0;
            float p = 0.f;
            if (lane < len) {
                int s = csrc[base + lane];
                float e = als[s] + aldn;
                e = e > 0.f ? e : LEAKY * e;
                p = __expf(e - m);
                sreg = s << 7;
                d += p;
            }
            int maxit = (len + 3) >> 2;
#pragma unroll 4
            for (int i = 0; i < maxit; i++) {
                int c = eg + i * 4;
                int soff = __shfl(sreg, c);
                float pc = __shfl(p, c);
                const float* srow = h + (size_t)(unsigned)soff + fl;
                a0 += pc * *(const f4_t*)(srow);
                a1 += pc * *(const f4_t*)(srow + 4);
            }
        }
    }

    float pself = __expf(selfe - m);
    if (eg == 0) {
        const float* srow = h + (size_t)n * 128 + fl;
        a0 += pself * *(const f4_t*)(srow);
        a1 += pself * *(const f4_t*)(srow + 4);
    }
#pragma unroll
    for (int j = 0; j < 4; j++) {
        a0[j] += __shfl_xor(a0[j], 16);
        a0[j] += __shfl_xor(a0[j], 32);
        a1[j] += __shfl_xor(a1[j], 16);
        a1[j] += __shfl_xor(a1[j], 32);
    }
#pragma unroll
    for (int off = 1; off < 64; off <<= 1) d += __shfl_xor(d, off);
    float r = 1.0f / (d + pself + EPS_DEN);

    if (lane < 16) {
        int fo = lane * 8;
        f4_t b0 = *(const f4_t*)(bias + fo);
        f4_t b1 = *(const f4_t*)(bias + fo + 4);
        f4_t o0, o1;
#pragma unroll
        for (int j = 0; j < 4; j++) {
            o0[j] = a0[j] * r + b0[j];
            o1[j] = a1[j] * r + b1[j];
        }
        *(f4_t*)&semb[wave][fo] = o0;
        *(f4_t*)&semb[wave][fo + 4] = o1;
        *(f4_t*)&emb[(size_t)n * 128 + fo] = o0;
        *(f4_t*)&emb[(size_t)n * 128 + fo + 4] = o1;
    }
    __syncthreads();

    float cacc = bc1[lane];
#pragma unroll 8
    for (int k = 0; k < 128; k++) cacc += semb[wave][k] * sW[k * 64 + lane];
    cacc = fmaxf(cacc, 0.f);
    float o0 = cacc * Wc2[lane * 2 + 0];
    float o1 = cacc * Wc2[lane * 2 + 1];
#pragma unroll
    for (int off = 32; off; off >>= 1) {
        o0 += __shfl_down(o0, off);
        o1 += __shfl_down(o1, off);
    }
    if (lane == 0) {
        outp[n * 2 + 0] = o0 + bc2[0];
        outp[n * 2 + 1] = o1 + bc2[1];
    }
}

// ---------------------------------------------------------------------------
extern "C" void kernel_launch(void* const* d_in, const int* in_sizes, int n_in,
                              void* d_out, int out_size, void* d_ws, size_t ws_size,
                              hipStream_t stream) {
    const float* x      = (const float*)d_in[0];
    const int*   ei     = (const int*)d_in[1];
    const float* W1     = (const float*)d_in[2];
    const float* a1s    = (const float*)d_in[3];
    const float* a1d    = (const float*)d_in[4];
    const float* b1     = (const float*)d_in[5];
    const float* W2     = (const float*)d_in[6];
    const float* a2s    = (const float*)d_in[7];
    const float* a2d    = (const float*)d_in[8];
    const float* b2     = (const float*)d_in[9];
    const float* W3     = (const float*)d_in[10];
    const float* a3s    = (const float*)d_in[11];
    const float* a3d    = (const float*)d_in[12];
    const float* b3     = (const float*)d_in[13];
    const float* Wc1    = (const float*)d_in[14];
    const float* bc1    = (const float*)d_in[15];
    const float* Wc2    = (const float*)d_in[16];
    const float* bc2    = (const float*)d_in[17];

    const int N = in_sizes[0] / 256;       // 10000
    const int E = in_sizes[1] / 2;         // 320000
    const int F = 512;

    const int* src = ei;
    const int* dst = ei + E;

    auto align = [](size_t o) { return (o + 255) & ~(size_t)255; };
    size_t o = 0;
    size_t o_G     = o; o = align(o + (size_t)N * F * 4);
    size_t o_ahi   = o; o = align(o + (size_t)N * F * 2);
    size_t o_alo   = o; o = align(o + (size_t)N * F * 2);
    size_t o_xhi   = o; o = align(o + (size_t)N * 256 * 2);
    size_t o_xlo   = o; o = align(o + (size_t)N * 256 * 2);
    size_t o_w1h   = o; o = align(o + (size_t)512 * 256 * 2);
    size_t o_w1l   = o; o = align(o + (size_t)512 * 256 * 2);
    size_t o_w2h   = o; o = align(o + (size_t)512 * 512 * 2);
    size_t o_w2l   = o; o = align(o + (size_t)512 * 512 * 2);
    size_t o_w3h   = o; o = align(o + (size_t)128 * 512 * 2);
    size_t o_w3l   = o; o = align(o + (size_t)128 * 512 * 2);
    size_t o_als   = o; o = align(o + (size_t)N * 4 * 4);
    size_t o_ald   = o; o = align(o + (size_t)N * 4 * 4);
    size_t o_psf   = o; o = align(o + (size_t)N * 4 * 4);
    size_t o_rden  = o; o = align(o + (size_t)N * 4 * 4);
    size_t o_cnt   = o; o = align(o + (size_t)N * 4);
    size_t o_off   = o; o = align(o + (size_t)(N + 1) * 4);
    size_t o_bsum  = o; o = align(o + (size_t)64 * 4);
    size_t o_csrc  = o; o = align(o + (size_t)E * 4);
    size_t o_ebuf  = o; o = align(o + (size_t)E * 4 * 8);   // int2 per (head,edge)
    (void)ws_size;

    char* ws = (char*)d_ws;
    float* bufG  = (float*)(ws + o_G);
    unsigned short* act_hi = (unsigned short*)(ws + o_ahi);
    unsigned short* act_lo = (unsigned short*)(ws + o_alo);
    unsigned short* x_hi   = (unsigned short*)(ws + o_xhi);
    unsigned short* x_lo   = (unsigned short*)(ws + o_xlo);
    unsigned short* w1h = (unsigned short*)(ws + o_w1h);
    unsigned short* w1l = (unsigned short*)(ws + o_w1l);
    unsigned short* w2h = (unsigned short*)(ws + o_w2h);
    unsigned short* w2l = (unsigned short*)(ws + o_w2l);
    unsigned short* w3h = (unsigned short*)(ws + o_w3h);
    unsigned short* w3l = (unsigned short*)(ws + o_w3l);
    float* als  = (float*)(ws + o_als);
    float* ald  = (float*)(ws + o_ald);
    float* psf  = (float*)(ws + o_psf);
    float* rden = (float*)(ws + o_rden);
    int*   cnt  = (int*)(ws + o_cnt);
    int*   offs = (int*)(ws + o_off);
    int*   bsum = (int*)(ws + o_bsum);
    int*   csrc = (int*)(ws + o_csrc);
    int2*  ebuf2 = (int2*)(ws + o_ebuf);

    float* outp = (float*)d_out;                 // [N,2]
    float* emb  = (float*)d_out + (size_t)N * 2; // [N,128]

    // ---- merged hist + splits (1 dispatch; cnt zeroed first) ----
    hipMemsetAsync(cnt, 0, (size_t)N * 4, stream);
    int eb = (E + 255) / 256;     // 1250
    int NBX = N;                  // N*256/256
    hipLaunchKernelGGL(hist_split_kernel, dim3(eb + NBX + 512 + 1024 + 256), dim3(256), 0, stream,
                       dst, cnt, E, eb,
                       x, x_hi, x_lo, NBX, W1, w1h, w1l, W2, w2h, w2l, W3, w3h, w3l);

    // ---- CSR scan + scatter ----
    int nbs = (N + 255) / 256;   // 40
    hipLaunchKernelGGL(scan1_kernel, dim3(nbs), dim3(256), 0, stream, cnt, bsum, N);
    hipLaunchKernelGGL(scan3b_kernel, dim3(nbs), dim3(256), 0, stream, cnt, bsum, offs, N, nbs);
    hipLaunchKernelGGL(scatter_kernel, dim3(eb), dim3(256), 0, stream, src, dst, cnt, csrc, E);

    int nb4 = (N + 3) / 4;        // 2500
    int gy128 = (N + 127) / 128;  // 79
    int gy64  = (N + 63) / 64;    // 157

    // ---- layer 1 ----
    hipLaunchKernelGGL(mfma_gemm128_kernel, dim3(512 / 128, gy128), dim3(256), 0, stream,
                       x_hi, x_lo, w1h, w1l, a1s, a1d, bufG, als, ald, N, 512, 256);
    hipLaunchKernelGGL(stats_h4_kernel, dim3(nb4), dim3(256), 0, stream,
                       csrc, offs, als, ald, ebuf2, psf, rden, N, E);
    hipLaunchKernelGGL((gat_agg_hh_kernel<true>), dim3(N * 8), dim3(64), 0, stream,
                       bufG, ebuf2, psf, rden, offs, b1, act_hi, act_lo, N, E);

    // ---- layer 2 ----
    hipLaunchKernelGGL(mfma_gemm128_kernel, dim3(512 / 128, gy128), dim3(256), 0, stream,
                       act_hi, act_lo, w2h, w2l, a2s, a2d, bufG, als, ald, N, 512, 512);
    hipLaunchKernelGGL(stats_h4_kernel, dim3(nb4), dim3(256), 0, stream,
                       csrc, offs, als, ald, ebuf2, psf, rden, N, E);
    hipLaunchKernelGGL((gat_agg_hh_kernel<true>), dim3(N * 8), dim3(64), 0, stream,
                       bufG, ebuf2, psf, rden, offs, b2, act_hi, act_lo, N, E);

    // ---- layer 3 + classifier (stats fused in) ----
    hipLaunchKernelGGL(mfma_gemm64_kernel, dim3(128 / 128, gy64), dim3(256), 0, stream,
                       act_hi, act_lo, w3h, w3l, a3s, a3d, bufG, als, ald, N, 128, 512);
    hipLaunchKernelGGL(gat_agg_h1_cls_kernel, dim3(nb4), dim3(256), 0, stream,
                       bufG, als, ald, csrc, offs, b3, Wc1, bc1, Wc2, bc2, emb, outp, N);
}

// Round 16
// 347.630 us; speedup vs baseline: 1.0238x; 1.0238x over previous
//
#include <hip/hip_runtime.h>
#include <cstddef>

#define LEAKY 0.2f
#define EPS_DEN 1e-16f

typedef short bf8_t __attribute__((ext_vector_type(8)));   // 8 bf16 in 4 VGPRs
typedef float f4_t __attribute__((ext_vector_type(4)));
typedef unsigned short us4_t __attribute__((ext_vector_type(4)));

__device__ __forceinline__ unsigned short f2bf(float f) {   // RNE
    unsigned u = __float_as_uint(f);
    unsigned r = (u + 0x7fffu + ((u >> 16) & 1u)) >> 16;
    return (unsigned short)r;
}
__device__ __forceinline__ float bf2f(unsigned short h) {
    return __uint_as_float(((unsigned)h) << 16);
}

// ---------------------------------------------------------------------------
// CSR build: (hist merged into split_all) -> scan1 -> scan3b -> scatter
// ---------------------------------------------------------------------------
__global__ void scan1_kernel(int* __restrict__ cnt, int* __restrict__ bsum, int N) {
    __shared__ int s[256];
    int t = threadIdx.x;
    int i = blockIdx.x * 256 + t;
    int v = (i < N) ? cnt[i] : 0;
    s[t] = v;
    __syncthreads();
#pragma unroll
    for (int st = 1; st < 256; st <<= 1) {
        int add = (t >= st) ? s[t - st] : 0;
        __syncthreads();
        s[t] += add;
        __syncthreads();
    }
    if (i < N) cnt[i] = s[t] - v;
    if (t == 255) bsum[blockIdx.x] = s[255];
}

__global__ void scan3b_kernel(int* __restrict__ cnt, const int* __restrict__ bsum,
                              int* __restrict__ offs, int N, int NB) {
    __shared__ int sPre[64];
    __shared__ int sTot;
    int t = threadIdx.x;
    if (t < 64) {
        int v = (t < NB) ? bsum[t] : 0;
        int inc = v;
#pragma unroll
        for (int off = 1; off < 64; off <<= 1) {
            int u = __shfl_up(inc, off);
            if (t >= off) inc += u;
        }
        sPre[t] = inc - v;
        if (t == 63) sTot = inc;
    }
    __syncthreads();
    int i = blockIdx.x * 256 + t;
    if (i < N) {
        int o = cnt[i] + sPre[blockIdx.x];
        offs[i] = o;
        cnt[i] = o;
    }
    if (blockIdx.x == 0 && t == 0) offs[N] = sTot;
}

__global__ void scatter_kernel(const int* __restrict__ src, const int* __restrict__ dst,
                               int* __restrict__ cursor, int* __restrict__ csrc, int E) {
    int i = blockIdx.x * blockDim.x + threadIdx.x;
    if (i < E) {
        int d = dst[i];
        int pos = atomicAdd(&cursor[d], 1);
        csrc[pos] = src[i];
    }
}

// ---------------------------------------------------------------------------
// Merged kernel: edge histogram + x/W splits (all input-only work, 1 dispatch).
// ---------------------------------------------------------------------------
__global__ void hist_split_kernel(
    const int* __restrict__ dst, int* __restrict__ counts, int E, int EB,
    const float* __restrict__ x, unsigned short* __restrict__ xh, unsigned short* __restrict__ xl,
    int NBX,
    const float* __restrict__ W1, unsigned short* __restrict__ w1h, unsigned short* __restrict__ w1l,
    const float* __restrict__ W2, unsigned short* __restrict__ w2h, unsigned short* __restrict__ w2l,
    const float* __restrict__ W3, unsigned short* __restrict__ w3h, unsigned short* __restrict__ w3l) {
    int b = blockIdx.x, t = threadIdx.x;
    if (b < EB) {
        int i = b * 256 + t;
        if (i < E) atomicAdd(&counts[dst[i]], 1);
        return;
    }
    b -= EB;
    float v;
    unsigned short* ph;
    unsigned short* pl;
    int out;
    if (b < NBX) {
        int idx = b * 256 + t;
        v = x[idx];
        out = idx;
        ph = xh; pl = xl;
    } else if (b < NBX + 512) {                 // W1 [256,512] -> W1^T [512,256]
        int idx = (b - NBX) * 256 + t;
        v = W1[idx];
        int k = idx >> 9, n = idx & 511;
        out = n * 256 + k;
        ph = w1h; pl = w1l;
    } else if (b < NBX + 512 + 1024) {          // W2 [512,512] -> W2^T
        int idx = (b - NBX - 512) * 256 + t;
        v = W2[idx];
        int k = idx >> 9, n = idx & 511;
        out = n * 512 + k;
        ph = w2h; pl = w2l;
    } else {                                    // W3 [512,128] -> W3^T [128,512]
        int idx = (b - NBX - 1536) * 256 + t;
        v = W3[idx];
        int k = idx >> 7, n = idx & 127;
        out = n * 512 + k;
        ph = w3h; pl = w3l;
    }
    unsigned short hv = f2bf(v);
    ph[out] = hv;
    pl[out] = f2bf(v - bf2f(hv));
}

// ---------------------------------------------------------------------------
// MFMA GEMM (split-bf16, single-staged), 64x128 tile, BK=64.
// 628 blocks at N=512 -> 2.45 rounds of half-size blocks (tail smoothing vs
// 316 blocks = 1.23 rounds of full-size). LDS 49KB -> 3 blocks/CU.
// EPILOGUE: als/ald for the 64 rows; head = n0>>7, stride hs (4 or 1).
// ---------------------------------------------------------------------------
__global__ __launch_bounds__(256) void mfma_gemm_kernel(
    const unsigned short* __restrict__ Ahi, const unsigned short* __restrict__ Alo,
    const unsigned short* __restrict__ BThi, const unsigned short* __restrict__ BTlo,
    const float* __restrict__ a_src, const float* __restrict__ a_dst,
    float* __restrict__ C, float* __restrict__ als, float* __restrict__ ald,
    int M, int N, int K, int hs) {
    constexpr int BK = 64;
    __shared__ __align__(16) unsigned short sAh[64 * BK];    // 8 KB
    __shared__ __align__(16) unsigned short sAl[64 * BK];    // 8 KB
    __shared__ __align__(16) unsigned short sBh[128 * BK];   // 16 KB
    __shared__ __align__(16) unsigned short sBl[128 * BK];   // 16 KB
    __shared__ float sAls[64][2];
    __shared__ float sAld[64][2];
    int t = threadIdx.x;
    int w = t >> 6, lane = t & 63;
    int quad = lane >> 4, low = lane & 15;
    int m0 = blockIdx.y * 64, n0 = blockIdx.x * 128;
    int wm = (w & 1) * 32, wn = (w >> 1) * 64;

    f4_t acc[2][4];
#pragma unroll
    for (int i = 0; i < 2; i++)
#pragma unroll
        for (int j = 0; j < 4; j++) acc[i][j] = (f4_t){0.f, 0.f, 0.f, 0.f};

    int srow = lane >> 3;     // 0..7 (8 rows per load-instruction)
    int schunk = lane & 7;    // 0..7 (16B chunk within 128B k-row)

    for (int k0 = 0; k0 < K; k0 += BK) {
        __syncthreads();
        // A: 64 rows; wave w stages rows w*16 .. w*16+15 (2 insts of 8 rows)
#pragma unroll
        for (int inst = 0; inst < 2; inst++) {
            int rl = w * 16 + inst * 8 + srow;
            int gm = m0 + rl;
            if (gm >= M) gm = M - 1;
            size_t goff = (size_t)gm * K + k0 + schunk * 8;
            size_t loff = (size_t)(w * 16 + inst * 8) * 128;
            __builtin_amdgcn_global_load_lds(
                (const __attribute__((address_space(1))) void*)(Ahi + goff),
                (__attribute__((address_space(3))) void*)((char*)sAh + loff), 16, 0, 0);
            __builtin_amdgcn_global_load_lds(
                (const __attribute__((address_space(1))) void*)(Alo + goff),
                (__attribute__((address_space(3))) void*)((char*)sAl + loff), 16, 0, 0);
        }
        // B: 128 rows; wave w stages rows w*32 .. w*32+31 (4 insts)
#pragma unroll
        for (int inst = 0; inst < 4; inst++) {
            int rl = w * 32 + inst * 8 + srow;
            int gn = n0 + rl;
            size_t goff = (size_t)gn * K + k0 + schunk * 8;
            size_t loff = (size_t)(w * 32 + inst * 8) * 128;
            __builtin_amdgcn_global_load_lds(
                (const __attribute__((address_space(1))) void*)(BThi + goff),
                (__attribute__((address_space(3))) void*)((char*)sBh + loff), 16, 0, 0);
            __builtin_amdgcn_global_load_lds(
                (const __attribute__((address_space(1))) void*)(BTlo + goff),
                (__attribute__((address_space(3))) void*)((char*)sBl + loff), 16, 0, 0);
        }
        __syncthreads();

#pragma unroll
        for (int ks = 0; ks < 2; ks++) {
            int ko = ks * 32 + quad * 8;
            bf8_t afh[2], bfh[4], xx[4];
#pragma unroll
            for (int i = 0; i < 2; i++) {
                int row = wm + i * 16 + low;
                afh[i] = *(const bf8_t*)&sAh[row * BK + ko];
            }
#pragma unroll
            for (int j = 0; j < 4; j++) {
                int row = wn + j * 16 + low;
                bfh[j] = *(const bf8_t*)&sBh[row * BK + ko];
            }
#pragma unroll
            for (int i = 0; i < 2; i++)
#pragma unroll
                for (int j = 0; j < 4; j++)
                    acc[i][j] = __builtin_amdgcn_mfma_f32_16x16x32_bf16(afh[i], bfh[j], acc[i][j], 0, 0, 0);
#pragma unroll
            for (int j = 0; j < 4; j++) {
                int row = wn + j * 16 + low;
                xx[j] = *(const bf8_t*)&sBl[row * BK + ko];
            }
#pragma unroll
            for (int i = 0; i < 2; i++)
#pragma unroll
                for (int j = 0; j < 4; j++)
                    acc[i][j] = __builtin_amdgcn_mfma_f32_16x16x32_bf16(afh[i], xx[j], acc[i][j], 0, 0, 0);
#pragma unroll
            for (int i = 0; i < 2; i++) {
                int row = wm + i * 16 + low;
                xx[i] = *(const bf8_t*)&sAl[row * BK + ko];
            }
#pragma unroll
            for (int i = 0; i < 2; i++)
#pragma unroll
                for (int j = 0; j < 4; j++)
                    acc[i][j] = __builtin_amdgcn_mfma_f32_16x16x32_bf16(xx[i], bfh[j], acc[i][j], 0, 0, 0);
        }
    }

    // C store
#pragma unroll
    for (int i = 0; i < 2; i++) {
#pragma unroll
        for (int r = 0; r < 4; r++) {
            int gm = m0 + wm + i * 16 + quad * 4 + r;
            if (gm >= M) continue;
#pragma unroll
            for (int j = 0; j < 4; j++) {
                int gn = n0 + wn + j * 16 + low;
                C[(size_t)gm * N + gn] = acc[i][j][r];
            }
        }
    }

    // epilogue: als/ald for this block's rows; head = n0>>7, stride hs
    int hd = n0 >> 7;
    float as_[4], ad_[4];
#pragma unroll
    for (int j = 0; j < 4; j++) {
        int c = wn + j * 16 + low;
        as_[j] = a_src[hd * 128 + c];
        ad_[j] = a_dst[hd * 128 + c];
    }
    int chh = wn >> 6;
#pragma unroll
    for (int i = 0; i < 2; i++) {
#pragma unroll
        for (int r = 0; r < 4; r++) {
            float v = acc[i][0][r] * as_[0] + acc[i][1][r] * as_[1] +
                      acc[i][2][r] * as_[2] + acc[i][3][r] * as_[3];
            float vd = acc[i][0][r] * ad_[0] + acc[i][1][r] * ad_[1] +
                       acc[i][2][r] * ad_[2] + acc[i][3][r] * ad_[3];
#pragma unroll
            for (int off = 1; off < 16; off <<= 1) {
                v += __shfl_xor(v, off);
                vd += __shfl_xor(vd, off);
            }
            if (low == 0) {
                int row = wm + i * 16 + quad * 4 + r;
                sAls[row][chh] = v;
                sAld[row][chh] = vd;
            }
        }
    }
    __syncthreads();
    if (t < 64) {
        int gm = m0 + t;
        if (gm < M) {
            als[gm * hs + hd] = sAls[t][0] + sAls[t][1];
            ald[gm * hs + hd] = sAld[t][0] + sAld[t][1];
        }
    }
}

// ---------------------------------------------------------------------------
// Softmax stats (h4) -> PACKED int2 {s*512, p} head-major pbuf2[hd*E+slot];
// psf = unnorm self weight; rden = 1/(sum+eps). Fast path deg<=64.
// ---------------------------------------------------------------------------
__global__ void stats_h4_kernel(const int* __restrict__ csrc, const int* __restrict__ offs,
                                const float* __restrict__ als, const float* __restrict__ ald,
                                int2* __restrict__ pbuf2, float* __restrict__ psf,
                                float* __restrict__ rden, int N, int E) {
    int wave = threadIdx.x >> 6, lane = threadIdx.x & 63;
    int n = blockIdx.x * 4 + wave;
    if (n >= N) return;
    int hd = lane & 3, es = lane >> 2;
    float aldn = ald[n * 4 + hd];
    float selfe = als[n * 4 + hd] + aldn;
    selfe = selfe > 0.f ? selfe : LEAKY * selfe;
    int beg = offs[n], end = offs[n + 1];
    int deg = end - beg;
    int2* pb = pbuf2 + (size_t)hd * E;
    float m = selfe;
    float d = 0.f;
    if (deg <= 64) {
        float eR[4];
        int sR[4];
        int nch = (deg + 15) >> 4;
        for (int k = 0; k < nch; k++) {
            int idx = beg + k * 16 + es;
            float e = -1e30f;
            int s = 0;
            if (idx < end) {
                s = csrc[idx];
                e = als[s * 4 + hd] + aldn;
                e = e > 0.f ? e : LEAKY * e;
                m = fmaxf(m, e);
            }
            eR[k] = e;
            sR[k] = s;
        }
#pragma unroll
        for (int off = 4; off < 64; off <<= 1) m = fmaxf(m, __shfl_xor(m, off));
        for (int k = 0; k < nch; k++) {
            int idx = beg + k * 16 + es;
            if (idx < end) {
                float p = __expf(eR[k] - m);
                pb[idx] = make_int2(sR[k] << 9, __float_as_int(p));
                d += p;
            }
        }
    } else {
        for (int base = beg; base + es < end; base += 16) {
            int idx = base + es;
            int s = csrc[idx];
            float e = als[s * 4 + hd] + aldn;
            e = e > 0.f ? e : LEAKY * e;
            pb[idx] = make_int2(s << 9, __float_as_int(e));
            m = fmaxf(m, e);
        }
#pragma unroll
        for (int off = 4; off < 64; off <<= 1) m = fmaxf(m, __shfl_xor(m, off));
        for (int base = beg; base + es < end; base += 16) {
            int idx = base + es;
            int2 se = pb[idx];
            float p = __expf(__int_as_float(se.y) - m);
            pb[idx] = make_int2(se.x, __float_as_int(p));
            d += p;
        }
    }
#pragma unroll
    for (int off = 4; off < 64; off <<= 1) d += __shfl_xor(d, off);
    float pself = __expf(selfe - m);
    float r = 1.0f / (d + pself + EPS_DEN);
    if (es == 0) {
        psf[n * 4 + hd] = pself;
        rden[n * 4 + hd] = r;
    }
}

// ---------------------------------------------------------------------------
// HALF-HEAD aggregate: R8 2-barrier structure + packed int2 staging (frozen:
// 5-way bracketed floor at ~46.6us). hh=blockIdx&7 keeps 2.6MB L2 slice/XCD.
// ---------------------------------------------------------------------------
template <bool DO_ELU>
__global__ __launch_bounds__(64) void gat_agg_hh_kernel(
    const float* __restrict__ h, const int2* __restrict__ pbuf2,
    const float* __restrict__ psf, const float* __restrict__ rden,
    const int* __restrict__ offs, const float* __restrict__ bias,
    unsigned short* __restrict__ ohi, unsigned short* __restrict__ olo,
    int N, int E) {
    int gid = blockIdx.x;
    int hh = gid & 7;
    int n = gid >> 3;
    int head = hh >> 1;
    int lane = threadIdx.x;
    int eg = lane >> 4;
    int f0 = hh * 64 + (lane & 15) * 4;
    const int2* pb = pbuf2 + (size_t)head * E;

    __shared__ __align__(8) int2 sE[64];
    int beg = offs[n], end = offs[n + 1];

    f4_t acc = (f4_t){0.f, 0.f, 0.f, 0.f};
    for (int base = beg; base < end; base += 64) {
        int len = min(64, end - base);
        __syncthreads();
        if (lane < len) sE[lane] = pb[base + lane];
        __syncthreads();
#pragma unroll 8
        for (int c = eg; c < len; c += 4) {
            int2 se = sE[c];
            const float* srow = h + (size_t)(unsigned)se.x + f0;
            acc += __int_as_float(se.y) * *(const f4_t*)srow;
        }
    }
    if (eg == 0) {
        f4_t x = *(const f4_t*)(h + (size_t)n * 512 + f0);
        acc += psf[n * 4 + head] * x;
    }
#pragma unroll
    for (int j = 0; j < 4; j++) {
        acc[j] += __shfl_xor(acc[j], 16);
        acc[j] += __shfl_xor(acc[j], 32);
    }
    if (lane < 16) {
        float r = rden[n * 4 + head];
        f4_t b = *(const f4_t*)(bias + f0);
        us4_t hs, ls;
#pragma unroll
        for (int j = 0; j < 4; j++) {
            float o = acc[j] * r + b[j];
            if (DO_ELU) o = o > 0.f ? o : (__expf(o) - 1.0f);
            unsigned short hv = f2bf(o);
            hs[j] = hv;
            ls[j] = f2bf(o - bf2f(hv));
        }
        size_t idx = (size_t)n * 512 + f0;
        *(us4_t*)&ohi[idx] = hs;
        *(us4_t*)&olo[idx] = ls;
    }
}

// ---------------------------------------------------------------------------
// Layer-3: FUSED stats + aggregate + classifier; 4 nodes/block (256 thr),
// Wc1 staged in LDS. Per-wave gather via shfl with uniform trip counts.
// ---------------------------------------------------------------------------
__global__ __launch_bounds__(256) void gat_agg_h1_cls_kernel(
    const float* __restrict__ h, const float* __restrict__ als,
    const float* __restrict__ ald, const int* __restrict__ csrc,
    const int* __restrict__ offs, const float* __restrict__ bias,
    const float* __restrict__ Wc1, const float* __restrict__ bc1,
    const float* __restrict__ Wc2, const float* __restrict__ bc2,
    float* __restrict__ emb, float* __restrict__ outp, int N) {
    int tid = threadIdx.x;
    int wave = tid >> 6;
    int n = blockIdx.x * 4 + wave;
    int lane = tid & 63;
    int eg = lane >> 4;
    int fl = (lane & 15) * 8;
    __shared__ float sW[128 * 64];
    __shared__ float semb[4][128];

    for (int i = tid; i < 128 * 64; i += 256) sW[i] = Wc1[i];

    int beg = offs[n], end = offs[n + 1];
    int deg = end - beg;
    float aldn = ald[n];
    float selfe = als[n] + aldn;
    selfe = selfe > 0.f ? selfe : LEAKY * selfe;

    f4_t a0 = (f4_t){0.f, 0.f, 0.f, 0.f};
    f4_t a1 = (f4_t){0.f, 0.f, 0.f, 0.f};
    float d = 0.f;
    float m;

    if (deg <= 64) {
        float e = -1e30f;
        int s = 0;
        if (lane < deg) {
            s = csrc[beg + lane];
            e = als[s] + aldn;
            e = e > 0.f ? e : LEAKY * e;
        }
        m = fmaxf(e, selfe);
#pragma unroll
        for (int off = 1; off < 64; off <<= 1) m = fmaxf(m, __shfl_xor(m, off));
        float p = (lane < deg) ? __expf(e - m) : 0.f;
        d = p;
        int sreg = s << 7;
        int maxit = (deg + 3) >> 2;
#pragma unroll 4
        for (int i = 0; i < maxit; i++) {
            int c = eg + i * 4;
            int soff = __shfl(sreg, c);
            float pc = __shfl(p, c);
            const float* srow = h + (size_t)(unsigned)soff + fl;
            a0 += pc * *(const f4_t*)(srow);
            a1 += pc * *(const f4_t*)(srow + 4);
        }
    } else {
        m = selfe;
        for (int i = beg + lane; i < end; i += 64) {
            int s = csrc[i];
            float e = als[s] + aldn;
            e = e > 0.f ? e : LEAKY * e;
            m = fmaxf(m, e);
        }
#pragma unroll
        for (int off = 1; off < 64; off <<= 1) m = fmaxf(m, __shfl_xor(m, off));
        for (int base = beg; base < end; base += 64) {
            int len = min(64, end - base);
            int sreg = 0;
            float p = 0.f;
            if (lane < len) {
                int s = csrc[base + lane];
                float e = als[s] + aldn;
                e = e > 0.f ? e : LEAKY * e;
                p = __expf(e - m);
                sreg = s << 7;
                d += p;
            }
            int maxit = (len + 3) >> 2;
#pragma unroll 4
            for (int i = 0; i < maxit; i++) {
                int c = eg + i * 4;
                int soff = __shfl(sreg, c);
                float pc = __shfl(p, c);
                const float* srow = h + (size_t)(unsigned)soff + fl;
                a0 += pc * *(const f4_t*)(srow);
                a1 += pc * *(const f4_t*)(srow + 4);
            }
        }
    }

    float pself = __expf(selfe - m);
    if (eg == 0) {
        const float* srow = h + (size_t)n * 128 + fl;
        a0 += pself * *(const f4_t*)(srow);
        a1 += pself * *(const f4_t*)(srow + 4);
    }
#pragma unroll
    for (int j = 0; j < 4; j++) {
        a0[j] += __shfl_xor(a0[j], 16);
        a0[j] += __shfl_xor(a0[j], 32);
        a1[j] += __shfl_xor(a1[j], 16);
        a1[j] += __shfl_xor(a1[j], 32);
    }
#pragma unroll
    for (int off = 1; off < 64; off <<= 1) d += __shfl_xor(d, off);
    float r = 1.0f / (d + pself + EPS_DEN);

    if (lane < 16) {
        int fo = lane * 8;
        f4_t b0 = *(const f4_t*)(bias + fo);
        f4_t b1 = *(const f4_t*)(bias + fo + 4);
        f4_t o0, o1;
#pragma unroll
        for (int j = 0; j < 4; j++) {
            o0[j] = a0[j] * r + b0[j];
            o1[j] = a1[j] * r + b1[j];
        }
        *(f4_t*)&semb[wave][fo] = o0;
        *(f4_t*)&semb[wave][fo + 4] = o1;
        *(f4_t*)&emb[(size_t)n * 128 + fo] = o0;
        *(f4_t*)&emb[(size_t)n * 128 + fo + 4] = o1;
    }
    __syncthreads();

    float cacc = bc1[lane];
#pragma unroll 8
    for (int k = 0; k < 128; k++) cacc += semb[wave][k] * sW[k * 64 + lane];
    cacc = fmaxf(cacc, 0.f);
    float o0 = cacc * Wc2[lane * 2 + 0];
    float o1 = cacc * Wc2[lane * 2 + 1];
#pragma unroll
    for (int off = 32; off; off >>= 1) {
        o0 += __shfl_down(o0, off);
        o1 += __shfl_down(o1, off);
    }
    if (lane == 0) {
        outp[n * 2 + 0] = o0 + bc2[0];
        outp[n * 2 + 1] = o1 + bc2[1];
    }
}

// ---------------------------------------------------------------------------
extern "C" void kernel_launch(void* const* d_in, const int* in_sizes, int n_in,
                              void* d_out, int out_size, void* d_ws, size_t ws_size,
                              hipStream_t stream) {
    const float* x      = (const float*)d_in[0];
    const int*   ei     = (const int*)d_in[1];
    const float* W1     = (const float*)d_in[2];
    const float* a1s    = (const float*)d_in[3];
    const float* a1d    = (const float*)d_in[4];
    const float* b1     = (const float*)d_in[5];
    const float* W2     = (const float*)d_in[6];
    const float* a2s    = (const float*)d_in[7];
    const float* a2d    = (const float*)d_in[8];
    const float* b2     = (const float*)d_in[9];
    const float* W3     = (const float*)d_in[10];
    const float* a3s    = (const float*)d_in[11];
    const float* a3d    = (const float*)d_in[12];
    const float* b3     = (const float*)d_in[13];
    const float* Wc1    = (const float*)d_in[14];
    const float* bc1    = (const float*)d_in[15];
    const float* Wc2    = (const float*)d_in[16];
    const float* bc2    = (const float*)d_in[17];

    const int N = in_sizes[0] / 256;       // 10000
    const int E = in_sizes[1] / 2;         // 320000
    const int F = 512;

    const int* src = ei;
    const int* dst = ei + E;

    auto align = [](size_t o) { return (o + 255) & ~(size_t)255; };
    size_t o = 0;
    size_t o_G     = o; o = align(o + (size_t)N * F * 4);
    size_t o_ahi   = o; o = align(o + (size_t)N * F * 2);
    size_t o_alo   = o; o = align(o + (size_t)N * F * 2);
    size_t o_xhi   = o; o = align(o + (size_t)N * 256 * 2);
    size_t o_xlo   = o; o = align(o + (size_t)N * 256 * 2);
    size_t o_w1h   = o; o = align(o + (size_t)512 * 256 * 2);
    size_t o_w1l   = o; o = align(o + (size_t)512 * 256 * 2);
    size_t o_w2h   = o; o = align(o + (size_t)512 * 512 * 2);
    size_t o_w2l   = o; o = align(o + (size_t)512 * 512 * 2);
    size_t o_w3h   = o; o = align(o + (size_t)128 * 512 * 2);
    size_t o_w3l   = o; o = align(o + (size_t)128 * 512 * 2);
    size_t o_als   = o; o = align(o + (size_t)N * 4 * 4);
    size_t o_ald   = o; o = align(o + (size_t)N * 4 * 4);
    size_t o_psf   = o; o = align(o + (size_t)N * 4 * 4);
    size_t o_rden  = o; o = align(o + (size_t)N * 4 * 4);
    size_t o_cnt   = o; o = align(o + (size_t)N * 4);
    size_t o_off   = o; o = align(o + (size_t)(N + 1) * 4);
    size_t o_bsum  = o; o = align(o + (size_t)64 * 4);
    size_t o_csrc  = o; o = align(o + (size_t)E * 4);
    size_t o_ebuf  = o; o = align(o + (size_t)E * 4 * 8);   // int2 per (head,edge)
    (void)ws_size;

    char* ws = (char*)d_ws;
    float* bufG  = (float*)(ws + o_G);
    unsigned short* act_hi = (unsigned short*)(ws + o_ahi);
    unsigned short* act_lo = (unsigned short*)(ws + o_alo);
    unsigned short* x_hi   = (unsigned short*)(ws + o_xhi);
    unsigned short* x_lo   = (unsigned short*)(ws + o_xlo);
    unsigned short* w1h = (unsigned short*)(ws + o_w1h);
    unsigned short* w1l = (unsigned short*)(ws + o_w1l);
    unsigned short* w2h = (unsigned short*)(ws + o_w2h);
    unsigned short* w2l = (unsigned short*)(ws + o_w2l);
    unsigned short* w3h = (unsigned short*)(ws + o_w3h);
    unsigned short* w3l = (unsigned short*)(ws + o_w3l);
    float* als  = (float*)(ws + o_als);
    float* ald  = (float*)(ws + o_ald);
    float* psf  = (float*)(ws + o_psf);
    float* rden = (float*)(ws + o_rden);
    int*   cnt  = (int*)(ws + o_cnt);
    int*   offs = (int*)(ws + o_off);
    int*   bsum = (int*)(ws + o_bsum);
    int*   csrc = (int*)(ws + o_csrc);
    int2*  ebuf2 = (int2*)(ws + o_ebuf);

    float* outp = (float*)d_out;                 // [N,2]
    float* emb  = (float*)d_out + (size_t)N * 2; // [N,128]

    // ---- merged hist + splits ----
    hipMemsetAsync(cnt, 0, (size_t)N * 4, stream);
    int eb = (E + 255) / 256;     // 1250
    int NBX = N;
    hipLaunchKernelGGL(hist_split_kernel, dim3(eb + NBX + 512 + 1024 + 256), dim3(256), 0, stream,
                       dst, cnt, E, eb,
                       x, x_hi, x_lo, NBX, W1, w1h, w1l, W2, w2h, w2l, W3, w3h, w3l);

    // ---- CSR scan + scatter ----
    int nbs = (N + 255) / 256;   // 40
    hipLaunchKernelGGL(scan1_kernel, dim3(nbs), dim3(256), 0, stream, cnt, bsum, N);
    hipLaunchKernelGGL(scan3b_kernel, dim3(nbs), dim3(256), 0, stream, cnt, bsum, offs, N, nbs);
    hipLaunchKernelGGL(scatter_kernel, dim3(eb), dim3(256), 0, stream, src, dst, cnt, csrc, E);

    int nb4 = (N + 3) / 4;        // 2500
    int gy  = (N + 63) / 64;      // 157

    // ---- layer 1 ----
    hipLaunchKernelGGL(mfma_gemm_kernel, dim3(512 / 128, gy), dim3(256), 0, stream,
                       x_hi, x_lo, w1h, w1l, a1s, a1d, bufG, als, ald, N, 512, 256, 4);
    hipLaunchKernelGGL(stats_h4_kernel, dim3(nb4), dim3(256), 0, stream,
                       csrc, offs, als, ald, ebuf2, psf, rden, N, E);
    hipLaunchKernelGGL((gat_agg_hh_kernel<true>), dim3(N * 8), dim3(64), 0, stream,
                       bufG, ebuf2, psf, rden, offs, b1, act_hi, act_lo, N, E);

    // ---- layer 2 ----
    hipLaunchKernelGGL(mfma_gemm_kernel, dim3(512 / 128, gy), dim3(256), 0, stream,
                       act_hi, act_lo, w2h, w2l, a2s, a2d, bufG, als, ald, N, 512, 512, 4);
    hipLaunchKernelGGL(stats_h4_kernel, dim3(nb4), dim3(256), 0, stream,
                       csrc, offs, als, ald, ebuf2, psf, rden, N, E);
    hipLaunchKernelGGL((gat_agg_hh_kernel<true>), dim3(N * 8), dim3(64), 0, stream,
                       bufG, ebuf2, psf, rden, offs, b2, act_hi, act_lo, N, E);

    // ---- layer 3 + classifier (stats fused in) ----
    hipLaunchKernelGGL(mfma_gemm_kernel, dim3(128 / 128, gy), dim3(256), 0, stream,
                       act_hi, act_lo, w3h, w3l, a3s, a3d, bufG, als, ald, N, 128, 512, 1);
    hipLaunchKernelGGL(gat_agg_h1_cls_kernel, dim3(nb4), dim3(256), 0, stream,
                       bufG, als, ald, csrc, offs, b3, Wc1, bc1, Wc2, bc2, emb, outp, N);
}